// Round 1
// baseline (13899.081 us; speedup 1.0000x reference)
//
#include <hip/hip_runtime.h>
#include <cmath>

// Problem constants
#define B_ 256
#define F_ 2048
#define T_ 40
#define V_ 10000
#define L_ 20
#define ATTR_ 400
#define E_ 512
#define H_ 1024
#define A_ 512
#define D1_ 3584   // H + F + E
#define D2_ 3072   // H + F
#define NS_ 19     // L - 1 steps

__device__ __forceinline__ float sigm(float x) { return 1.0f / (1.0f + expf(-x)); }

// ---------------------------------------------------------------------------
// Generic C[M,N] = A[M,K] * B[N,K]^T (+ C if beta) (+ bias if non-null)
// A row-major lda, B row-major ldb (i.e. computes x @ W.T), C row-major ldc.
// grid: (ceil(N/64), M/64), block 256. K must be a multiple of 16, N of 4.
// ---------------------------------------------------------------------------
__global__ __launch_bounds__(256) void gemm_nt(
    const float* __restrict__ A, const float* __restrict__ B,
    float* __restrict__ C, const float* __restrict__ bias,
    int N, int K, int lda, int ldb, long ldc, int beta)
{
    constexpr int LDT = 68;
    __shared__ float As[16 * LDT];
    __shared__ float Bs[16 * LDT];
    const int tid  = threadIdx.x;
    const int n0   = blockIdx.x * 64;
    const int m0   = blockIdx.y * 64;
    const int tx   = tid & 15;        // n quad
    const int ty   = tid >> 4;        // m quad
    const int lrow = tid >> 2;        // 0..63 row for loads
    const int lcol = (tid & 3) * 4;   // 0,4,8,12 k offset for loads
    const bool bvalid = (n0 + lrow) < N;
    const float* Ap = A + (long)(m0 + lrow) * lda + lcol;
    const float* Bp = bvalid ? (B + (long)(n0 + lrow) * ldb + lcol) : B;

    float acc[4][4] = {};
    for (int k0 = 0; k0 < K; k0 += 16) {
        float4 a4 = *(const float4*)(Ap + k0);
        float4 b4 = *(const float4*)(Bp + k0);
        if (!bvalid) { b4.x = b4.y = b4.z = b4.w = 0.f; }
        __syncthreads();
        As[(lcol + 0) * LDT + lrow] = a4.x;
        As[(lcol + 1) * LDT + lrow] = a4.y;
        As[(lcol + 2) * LDT + lrow] = a4.z;
        As[(lcol + 3) * LDT + lrow] = a4.w;
        Bs[(lcol + 0) * LDT + lrow] = b4.x;
        Bs[(lcol + 1) * LDT + lrow] = b4.y;
        Bs[(lcol + 2) * LDT + lrow] = b4.z;
        Bs[(lcol + 3) * LDT + lrow] = b4.w;
        __syncthreads();
#pragma unroll
        for (int k = 0; k < 16; ++k) {
            float4 av = *(const float4*)&As[k * LDT + ty * 4];
            float4 bv = *(const float4*)&Bs[k * LDT + tx * 4];
            float a_[4] = {av.x, av.y, av.z, av.w};
            float b_[4] = {bv.x, bv.y, bv.z, bv.w};
#pragma unroll
            for (int i = 0; i < 4; ++i)
#pragma unroll
                for (int j = 0; j < 4; ++j)
                    acc[i][j] += a_[i] * b_[j];
        }
    }
    const int n = n0 + tx * 4;
    if (n < N) {
        float4 bb = {0.f, 0.f, 0.f, 0.f};
        if (bias) bb = *(const float4*)(bias + n);
#pragma unroll
        for (int i = 0; i < 4; ++i) {
            long off = (long)(m0 + ty * 4 + i) * ldc + n;
            float4 cv = {acc[i][0] + bb.x, acc[i][1] + bb.y,
                         acc[i][2] + bb.z, acc[i][3] + bb.w};
            if (beta) {
                float4 o = *(const float4*)(C + off);
                cv.x += o.x; cv.y += o.y; cv.z += o.z; cv.w += o.w;
            }
            *(float4*)(C + off) = cv;
        }
    }
}

// ---------------------------------------------------------------------------
// embed_f[b,t,a] = sum_f feats[b,f,t] * attf_W[a,f] + attf_b[a]
// grid: (A/64, B), block 256
// ---------------------------------------------------------------------------
__global__ __launch_bounds__(256) void embedf_kernel(
    const float* __restrict__ feats, const float* __restrict__ W,
    const float* __restrict__ bias, float* __restrict__ out)
{
    constexpr int LDA = 44, LDB = 68;
    __shared__ float As[16 * LDA];   // [k=f][m=t]
    __shared__ float Bs[16 * LDB];   // [k=f][n=a]
    const int b  = blockIdx.y;
    const int a0 = blockIdx.x * 64;
    const int tid = threadIdx.x;
    const int tx = tid & 15, ty = tid >> 4;
    const int lrow = tid >> 2, lcol = (tid & 3) * 4;
    const float* fb = feats + (long)b * F_ * T_;
    const float* Bp = W + (long)(a0 + lrow) * F_ + lcol;

    float acc[3][4] = {};
    for (int f0 = 0; f0 < F_; f0 += 16) {
        float4 b4 = *(const float4*)(Bp + f0);
        __syncthreads();
        for (int idx = tid; idx < 16 * T_; idx += 256) {
            int fr = idx / T_;
            int t  = idx - fr * T_;
            As[fr * LDA + t] = fb[(long)(f0 + fr) * T_ + t];
        }
        Bs[(lcol + 0) * LDB + lrow] = b4.x;
        Bs[(lcol + 1) * LDB + lrow] = b4.y;
        Bs[(lcol + 2) * LDB + lrow] = b4.z;
        Bs[(lcol + 3) * LDB + lrow] = b4.w;
        __syncthreads();
#pragma unroll
        for (int k = 0; k < 16; ++k) {
            float4 bv = *(const float4*)&Bs[k * LDB + tx * 4];
            float b_[4] = {bv.x, bv.y, bv.z, bv.w};
            float a0v = As[k * LDA + ty];
            float a1v = As[k * LDA + ty + 16];
            float a2v = (ty < 8) ? As[k * LDA + ty + 32] : 0.f;
#pragma unroll
            for (int j = 0; j < 4; ++j) {
                acc[0][j] += a0v * b_[j];
                acc[1][j] += a1v * b_[j];
                acc[2][j] += a2v * b_[j];
            }
        }
    }
    const int a = a0 + tx * 4;
    float4 bb = *(const float4*)(bias + a);
    int ms[3] = {ty, ty + 16, ty + 32};
#pragma unroll
    for (int i = 0; i < 3; ++i) {
        int t = ms[i];
        if (t < T_) {
            long off = ((long)b * T_ + t) * A_ + a;
            float4 cv = {acc[i][0] + bb.x, acc[i][1] + bb.y,
                         acc[i][2] + bb.z, acc[i][3] + bb.w};
            *(float4*)(out + off) = cv;
        }
    }
}

// mean over T: mf[b,f]
__global__ void mean_kernel(const float* __restrict__ feats, float* __restrict__ mf)
{
    int idx = blockIdx.x * 256 + threadIdx.x;    // b*F + f
    const float* p = feats + (long)idx * T_;
    float s = 0.f;
#pragma unroll
    for (int t = 0; t < T_; t += 4) {
        float4 v = *(const float4*)(p + t);
        s += v.x + v.y + v.z + v.w;
    }
    mf[idx] = s * (1.0f / (float)T_);
}

__global__ void build_x1_kernel(const float* __restrict__ h2, const float* __restrict__ mf,
                                const int* __restrict__ sents, const float* __restrict__ emb,
                                float* __restrict__ x1, int s)
{
    int idx = blockIdx.x * 256 + threadIdx.x;
    int b = idx / D1_, d = idx - b * D1_;
    float v;
    if (d < H_)            v = h2[b * H_ + d];
    else if (d < H_ + F_)  v = mf[b * F_ + (d - H_)];
    else {
        int wd = sents[b * L_ + s];
        v = emb[(long)wd * E_ + (d - H_ - F_)];
    }
    x1[idx] = v;
}

__global__ void build_x2_kernel(const float* __restrict__ h1, const float* __restrict__ vh,
                                float* __restrict__ x2)
{
    int idx = blockIdx.x * 256 + threadIdx.x;
    int b = idx / D2_, d = idx - b * D2_;
    x2[idx] = (d < H_) ? h1[b * H_ + d] : vh[b * F_ + d - H_];
}

// gate order i, f, g, o (jnp.split axis=1)
__global__ void lstm_elem_kernel(const float* __restrict__ g,
                                 const float* __restrict__ bih, const float* __restrict__ bhh,
                                 float* __restrict__ h, float* __restrict__ c)
{
    int idx = blockIdx.x * 256 + threadIdx.x;
    int b = idx >> 10, j = idx & 1023;
    const float* gr = g + (long)b * (4 * H_);
    float ig = gr[j]           + bih[j]           + bhh[j];
    float fg = gr[H_ + j]      + bih[H_ + j]      + bhh[H_ + j];
    float gg = gr[2 * H_ + j]  + bih[2 * H_ + j]  + bhh[2 * H_ + j];
    float og = gr[3 * H_ + j]  + bih[3 * H_ + j]  + bhh[3 * H_ + j];
    float cn = sigm(fg) * c[idx] + sigm(ig) * tanhf(gg);
    c[idx] = cn;
    h[idx] = sigm(og) * tanhf(cn);
}

// scores[b,t] = sum_a tanh(ef[b,t,a] + eh[b,a] + atth_b[a]) * atta_W[a] + atta_b
// block = 4 waves, each wave one (b,t); grid = B*T/4
__global__ __launch_bounds__(256) void scores_kernel(
    const float* __restrict__ ef, const float* __restrict__ eh,
    const float* __restrict__ atth_b, const float* __restrict__ atta_W,
    const float* __restrict__ atta_b, float* __restrict__ scores)
{
    int wv = threadIdx.x >> 6, lane = threadIdx.x & 63;
    int pair = blockIdx.x * 4 + wv;
    int b = pair / T_, t = pair - b * T_;
    const float* e   = ef + ((long)b * T_ + t) * A_;
    const float* ehb = eh + (long)b * A_;
    float s = 0.f;
#pragma unroll
    for (int i = 0; i < 2; ++i) {
        int a = lane * 8 + i * 4;
        float4 ev = *(const float4*)(e + a);
        float4 hv = *(const float4*)(ehb + a);
        float4 hb = *(const float4*)(atth_b + a);
        float4 aw = *(const float4*)(atta_W + a);
        s += tanhf(ev.x + hv.x + hb.x) * aw.x;
        s += tanhf(ev.y + hv.y + hb.y) * aw.y;
        s += tanhf(ev.z + hv.z + hb.z) * aw.z;
        s += tanhf(ev.w + hv.w + hb.w) * aw.w;
    }
#pragma unroll
    for (int o = 32; o > 0; o >>= 1) s += __shfl_down(s, o, 64);
    if (lane == 0) scores[pair] = s + atta_b[0];
}

// softmax over T per b; block = 64 threads, grid = B
__global__ void softmax_kernel(const float* __restrict__ scores, float* __restrict__ alpha)
{
    int b = blockIdx.x, t = threadIdx.x;
    float v = (t < T_) ? scores[b * T_ + t] : -INFINITY;
    float m = v;
#pragma unroll
    for (int o = 32; o > 0; o >>= 1) m = fmaxf(m, __shfl_down(m, o, 64));
    m = __shfl(m, 0, 64);
    float e = (t < T_) ? expf(v - m) : 0.f;
    float sum = e;
#pragma unroll
    for (int o = 32; o > 0; o >>= 1) sum += __shfl_down(sum, o, 64);
    sum = __shfl(sum, 0, 64);
    if (t < T_) alpha[b * T_ + t] = e / sum;
}

// v_hat[b,f] = sum_t alpha[b,t]*feats[b,f,t];  grid (F/256, B)
__global__ void vhat_kernel(const float* __restrict__ feats,
                            const float* __restrict__ alpha, float* __restrict__ vh)
{
    __shared__ float al[T_];
    int b = blockIdx.y;
    int f = blockIdx.x * 256 + threadIdx.x;
    if (threadIdx.x < T_) al[threadIdx.x] = alpha[b * T_ + threadIdx.x];
    __syncthreads();
    const float* p = feats + ((long)b * F_ + f) * T_;
    float s = 0.f;
#pragma unroll
    for (int t = 0; t < T_; t += 4) {
        float4 v = *(const float4*)(p + t);
        s += al[t] * v.x + al[t + 1] * v.y + al[t + 2] * v.z + al[t + 3] * v.w;
    }
    vh[(long)b * F_ + f] = s;
}

// argmax over V of preds row; first-index tie-break; writes float index
__global__ __launch_bounds__(256) void argmax_kernel(
    const float* __restrict__ preds, float* __restrict__ outw, int s)
{
    __shared__ float sv[256];
    __shared__ int   si[256];
    int b = blockIdx.x, tid = threadIdx.x;
    const float* row = preds + (long)b * ((long)NS_ * V_);
    float best = -INFINITY; int bi = 0x7fffffff;
    for (int v = tid; v < V_; v += 256) {
        float x = row[v];
        if (x > best) { best = x; bi = v; }
    }
    sv[tid] = best; si[tid] = bi;
    __syncthreads();
    for (int o = 128; o > 0; o >>= 1) {
        if (tid < o) {
            float ov = sv[tid + o]; int oi = si[tid + o];
            if (ov > sv[tid] || (ov == sv[tid] && oi < si[tid])) { sv[tid] = ov; si[tid] = oi; }
        }
        __syncthreads();
    }
    if (tid == 0) outw[b * NS_ + s] = (float)si[0];
}

extern "C" void kernel_launch(void* const* d_in, const int* in_sizes, int n_in,
                              void* d_out, int out_size, void* d_ws, size_t ws_size,
                              hipStream_t stream)
{
    const float* feats  = (const float*)d_in[0];
    const float* atts   = (const float*)d_in[1];
    const int*   sents  = (const int*)d_in[2];
    const float* attr_W = (const float*)d_in[3];
    const float* attr_b = (const float*)d_in[4];
    const float* emb    = (const float*)d_in[5];
    const float* l1_Wih = (const float*)d_in[6];
    const float* l1_Whh = (const float*)d_in[7];
    const float* l1_bih = (const float*)d_in[8];
    const float* l1_bhh = (const float*)d_in[9];
    const float* l2_Wih = (const float*)d_in[10];
    const float* l2_Whh = (const float*)d_in[11];
    const float* l2_bih = (const float*)d_in[12];
    const float* l2_bhh = (const float*)d_in[13];
    const float* prob_W = (const float*)d_in[14];
    const float* prob_b = (const float*)d_in[15];
    const float* attf_W = (const float*)d_in[16];
    const float* attf_b = (const float*)d_in[17];
    const float* atth_W = (const float*)d_in[18];
    const float* atth_b = (const float*)d_in[19];
    const float* atta_W = (const float*)d_in[20];
    const float* atta_b = (const float*)d_in[21];

    float* out = (float*)d_out;
    float* preds_out = out + B_ * NS_;   // 4864 floats of argmax indices first

    float* w = (float*)d_ws;
    float* mf     = w;  w += (long)B_ * F_;
    float* ef     = w;  w += (long)B_ * T_ * A_;
    float* attr_v = w;  w += (long)B_ * D2_;
    float* h1     = w;  w += (long)B_ * H_;
    float* c1     = w;  w += (long)B_ * H_;
    float* h2     = w;  w += (long)B_ * H_;
    float* c2     = w;  w += (long)B_ * H_;
    float* x1     = w;  w += (long)B_ * D1_;
    float* x2     = w;  w += (long)B_ * D2_;
    float* g1     = w;  w += (long)B_ * 4 * H_;
    float* g2     = w;  w += (long)B_ * 4 * H_;
    float* ehb    = w;  w += (long)B_ * A_;
    float* sc     = w;  w += (long)B_ * T_;
    float* al     = w;  w += (long)B_ * T_;
    float* vh     = w;  w += (long)B_ * F_;

    // h1,c1,h2,c2 are contiguous: zero them (ws is poisoned 0xAA each call)
    hipMemsetAsync(h1, 0, (size_t)4 * B_ * H_ * sizeof(float), stream);

    // Precompute
    mean_kernel<<<B_ * F_ / 256, 256, 0, stream>>>(feats, mf);
    embedf_kernel<<<dim3(A_ / 64, B_), 256, 0, stream>>>(feats, attf_W, attf_b, ef);
    gemm_nt<<<dim3(D2_ / 64, B_ / 64), 256, 0, stream>>>(
        atts, attr_W, attr_v, attr_b, D2_, ATTR_, ATTR_, ATTR_, D2_, 0);
    gemm_nt<<<dim3(4 * H_ / 64, B_ / 64), 256, 0, stream>>>(
        attr_v, l2_Wih, g2, nullptr, 4 * H_, D2_, D2_, D2_, 4 * H_, 0);
    lstm_elem_kernel<<<B_ * H_ / 256, 256, 0, stream>>>(g2, l2_bih, l2_bhh, h2, c2);

    for (int s = 0; s < NS_; ++s) {
        build_x1_kernel<<<B_ * D1_ / 256, 256, 0, stream>>>(h2, mf, sents, emb, x1, s);
        gemm_nt<<<dim3(64, 4), 256, 0, stream>>>(
            x1, l1_Wih, g1, nullptr, 4 * H_, D1_, D1_, D1_, 4 * H_, 0);
        gemm_nt<<<dim3(64, 4), 256, 0, stream>>>(
            h1, l1_Whh, g1, nullptr, 4 * H_, H_, H_, H_, 4 * H_, 1);
        lstm_elem_kernel<<<B_ * H_ / 256, 256, 0, stream>>>(g1, l1_bih, l1_bhh, h1, c1);

        gemm_nt<<<dim3(A_ / 64, 4), 256, 0, stream>>>(
            h1, atth_W, ehb, nullptr, A_, H_, H_, H_, A_, 0);
        scores_kernel<<<B_ * T_ / 4, 256, 0, stream>>>(ef, ehb, atth_b, atta_W, atta_b, sc);
        softmax_kernel<<<B_, 64, 0, stream>>>(sc, al);
        vhat_kernel<<<dim3(F_ / 256, B_), 256, 0, stream>>>(feats, al, vh);

        build_x2_kernel<<<B_ * D2_ / 256, 256, 0, stream>>>(h1, vh, x2);
        gemm_nt<<<dim3(64, 4), 256, 0, stream>>>(
            x2, l2_Wih, g2, nullptr, 4 * H_, D2_, D2_, D2_, 4 * H_, 0);
        gemm_nt<<<dim3(64, 4), 256, 0, stream>>>(
            h2, l2_Whh, g2, nullptr, 4 * H_, H_, H_, H_, 4 * H_, 1);
        lstm_elem_kernel<<<B_ * H_ / 256, 256, 0, stream>>>(g2, l2_bih, l2_bhh, h2, c2);

        gemm_nt<<<dim3((V_ + 63) / 64, 4), 256, 0, stream>>>(
            h2, prob_W, preds_out + (long)s * V_, prob_b, V_, H_, H_, H_, (long)NS_ * V_, 0);
        argmax_kernel<<<B_, 256, 0, stream>>>(preds_out + (long)s * V_, out, s);
    }
}

// Round 2
// 8148.555 us; speedup vs baseline: 1.7057x; 1.7057x over previous
//
#include <hip/hip_runtime.h>
#include <cmath>

#define B_ 256
#define F_ 2048
#define T_ 40
#define V_ 10000
#define L_ 20
#define ATTR_ 400
#define E_ 512
#define H_ 1024
#define A_ 512
#define D1_ 3584
#define D2_ 3072
#define NS_ 19

__device__ __forceinline__ float sigm(float x) { return 1.0f / (1.0f + expf(-x)); }

// ---------------------------------------------------------------------------
// TN GEMM: C[n][m] (CT) or C[m][n] (CN) = sum_k A[n][k] * B[k][m]
// A row-major lda (weights), B k-major with row stride 256 (transposed acts).
// Tile 64n x 128m, 256 threads, 4n x 8m per thread. blockIdx.z picks a K-chunk
// (independent weight region); partial results land in out + z*zstride.
// BMODE==1: B is feats[b][f][t] addressed as [k=f][m=(b,t)] (embedf only).
// ---------------------------------------------------------------------------
struct GemmChunk { const float* A; const float* B; int lda; int kc; };
struct Chunks8 { GemmChunk c[8]; };

template<int CN, int BMODE>
__global__ __launch_bounds__(256) void gemm_tn(
    Chunks8 ch, float* out, const float* bias, const float* feats,
    int Nreal, long ldc, long zstride, int partial)
{
    const GemmChunk cc = ch.c[blockIdx.z];
    const int tid = threadIdx.x;
    const int n0 = blockIdx.x * 64;
    const int m0 = blockIdx.y * 128;
    const int tn = tid >> 4;        // 0..15 n-quad
    const int tm = tid & 15;        // 0..15 m-group
    __shared__ float As[16 * 68];
    __shared__ float Bs[16 * 128];

    // A staging: 64 rows x 16 k, one float4 per thread
    const int an = tid >> 2;
    const int ak = (tid & 3) * 4;
    int arow = n0 + an; if (arow >= Nreal) arow = Nreal - 1;
    const float* Ap = cc.A + (long)arow * cc.lda + ak;

    // B staging: 16 k-rows x 128 m, two float4 per thread
    const int bk = tid >> 5;        // 0..7
    const int bm = (tid & 31) * 4;  // 0..124
    const float* Bp = nullptr;
    long fa0 = 0, fa1 = 0, fa2 = 0, fa3 = 0;
    if (BMODE == 0) {
        Bp = cc.B + (long)bk * 256 + m0 + bm;
    } else {
        int mm = m0 + bm;
        int b0g = mm / T_,       t0g = mm - b0g * T_;
        int b1g = (mm+1) / T_,   t1g = (mm+1) - b1g * T_;
        int b2g = (mm+2) / T_,   t2g = (mm+2) - b2g * T_;
        int b3g = (mm+3) / T_,   t3g = (mm+3) - b3g * T_;
        fa0 = (long)b0g * (F_*T_) + t0g;
        fa1 = (long)b1g * (F_*T_) + t1g;
        fa2 = (long)b2g * (F_*T_) + t2g;
        fa3 = (long)b3g * (F_*T_) + t3g;
    }

    float acc[4][8];
#pragma unroll
    for (int i = 0; i < 4; ++i)
#pragma unroll
        for (int j = 0; j < 8; ++j) acc[i][j] = 0.f;

    for (int kk = 0; kk < cc.kc; kk += 16) {
        float4 a4 = *(const float4*)Ap; Ap += 16;
        float4 b4a, b4b;
        if (BMODE == 0) {
            b4a = *(const float4*)Bp;
            b4b = *(const float4*)(Bp + 8 * 256);
            Bp += 16 * 256;
        } else {
            long f1 = (long)(kk + bk) * T_;
            long f2 = (long)(kk + bk + 8) * T_;
            b4a.x = feats[fa0 + f1]; b4a.y = feats[fa1 + f1];
            b4a.z = feats[fa2 + f1]; b4a.w = feats[fa3 + f1];
            b4b.x = feats[fa0 + f2]; b4b.y = feats[fa1 + f2];
            b4b.z = feats[fa2 + f2]; b4b.w = feats[fa3 + f2];
        }
        __syncthreads();
        As[(ak + 0) * 68 + an] = a4.x;
        As[(ak + 1) * 68 + an] = a4.y;
        As[(ak + 2) * 68 + an] = a4.z;
        As[(ak + 3) * 68 + an] = a4.w;
        *(float4*)&Bs[bk * 128 + bm]       = b4a;
        *(float4*)&Bs[(bk + 8) * 128 + bm] = b4b;
        __syncthreads();
#pragma unroll
        for (int k = 0; k < 16; ++k) {
            float4 av = *(const float4*)&As[k * 68 + tn * 4];
            float4 b1 = *(const float4*)&Bs[k * 128 + tm * 4];
            float4 b2 = *(const float4*)&Bs[k * 128 + tm * 4 + 64];
            const float a_[4] = {av.x, av.y, av.z, av.w};
            const float b_[8] = {b1.x, b1.y, b1.z, b1.w, b2.x, b2.y, b2.z, b2.w};
#pragma unroll
            for (int i = 0; i < 4; ++i)
#pragma unroll
                for (int j = 0; j < 8; ++j)
                    acc[i][j] += a_[i] * b_[j];
        }
    }

    if (CN == 0) {
        float* P = out + (long)blockIdx.z * zstride;
#pragma unroll
        for (int i = 0; i < 4; ++i) {
            long row = (long)(n0 + tn * 4 + i) * 256 + m0;
            float4 v1 = {acc[i][0], acc[i][1], acc[i][2], acc[i][3]};
            float4 v2 = {acc[i][4], acc[i][5], acc[i][6], acc[i][7]};
            *(float4*)&P[row + tm * 4]      = v1;
            *(float4*)&P[row + tm * 4 + 64] = v2;
        }
    } else {
        const int n = n0 + tn * 4;
        if (n < Nreal) {
            float4 bb = {0.f, 0.f, 0.f, 0.f};
            if (bias) bb = *(const float4*)(bias + n);
            float* P = partial ? (out + (long)blockIdx.z * zstride) : out;
#pragma unroll
            for (int j = 0; j < 8; ++j) {
                int m = m0 + tm * 4 + (j < 4 ? j : 60 + j);
                float4 v = {acc[0][j] + bb.x, acc[1][j] + bb.y,
                            acc[2][j] + bb.z, acc[3][j] + bb.w};
                *(float4*)&P[(long)m * ldc + n] = v;
            }
        }
    }
}

// out[e] = sum_z P[z*zstride+e]  (+ base[e] if mode==1, + base[e>>8] if mode==2)
__global__ void reduce_ct(float* __restrict__ out, const float* __restrict__ P,
                          const float* __restrict__ base,
                          int S, long zstride, int n_elems, int mode)
{
    long e = ((long)blockIdx.x * 256 + threadIdx.x) * 4;
    if (e >= n_elems) return;
    float4 s = *(const float4*)&P[e];
    for (int z = 1; z < S; ++z) {
        float4 p = *(const float4*)&P[(long)z * zstride + e];
        s.x += p.x; s.y += p.y; s.z += p.z; s.w += p.w;
    }
    if (mode == 1) {
        float4 bm = *(const float4*)&base[e];
        s.x += bm.x; s.y += bm.y; s.z += bm.z; s.w += bm.w;
    } else if (mode == 2) {
        float bv = base[e >> 8];
        s.x += bv; s.y += bv; s.z += bv; s.w += bv;
    }
    *(float4*)&out[e] = s;
}

// preds[b][s][v] = P0 + P1 + prob_b
__global__ void reduce_prob(const float* __restrict__ P, const float* __restrict__ pb,
                            float* __restrict__ dout, int s)
{
    int g = blockIdx.x * 256 + threadIdx.x;
    int b = g / 2500;
    int v = (g - b * 2500) * 4;
    float4 a = *(const float4*)&P[(long)b * 10048 + v];
    float4 c = *(const float4*)&P[256L * 10048 + (long)b * 10048 + v];
    float4 bb = *(const float4*)&pb[v];
    float4 r = {a.x + c.x + bb.x, a.y + c.y + bb.y, a.z + c.z + bb.z, a.w + c.w + bb.w};
    *(float4*)&dout[4864L + (long)b * (NS_ * (long)V_) + (long)s * V_ + v] = r;
}

// transposed LSTM elementwise: gT rows = [i|f|g|o] gates, idx = j*256+b
__global__ void lstm_kernel(const float* __restrict__ g, float* __restrict__ c,
                            float* __restrict__ hd1, float* __restrict__ hd2)
{
    int idx = blockIdx.x * 256 + threadIdx.x;
    float ig = g[idx];
    float fg = g[1024 * 256 + idx];
    float gg = g[2048 * 256 + idx];
    float og = g[3072 * 256 + idx];
    float cn = sigm(fg) * c[idx] + sigm(ig) * tanhf(gg);
    c[idx] = cn;
    float hv = sigm(og) * tanhf(cn);
    hd1[idx] = hv;
    hd2[idx] = hv;
}

// fused attention: scores -> softmax -> v_hat, one block per b
__global__ __launch_bounds__(256) void attention_kernel(
    const float* __restrict__ ef, const float* __restrict__ ehT,
    const float* __restrict__ feats, const float* __restrict__ atta_W,
    const float* __restrict__ atta_b, float* __restrict__ vh)
{
    __shared__ float eh_s[512], aw_s[512], sc_s[48];
    int b = blockIdx.x, tid = threadIdx.x;
    eh_s[tid]       = ehT[(long)tid * 256 + b];
    eh_s[tid + 256] = ehT[(long)(tid + 256) * 256 + b];
    aw_s[tid]       = atta_W[tid];
    aw_s[tid + 256] = atta_W[tid + 256];
    __syncthreads();
    int w = tid >> 6, lane = tid & 63;
    float ab0 = atta_b[0];
    for (int i = 0; i < 10; ++i) {
        int t = w * 10 + i;
        const float* ep = ef + ((long)b * T_ + t) * A_ + lane * 8;
        float4 e1 = *(const float4*)ep;
        float4 e2 = *(const float4*)(ep + 4);
        int a = lane * 8;
        float s = tanhf(e1.x + eh_s[a+0]) * aw_s[a+0] + tanhf(e1.y + eh_s[a+1]) * aw_s[a+1]
                + tanhf(e1.z + eh_s[a+2]) * aw_s[a+2] + tanhf(e1.w + eh_s[a+3]) * aw_s[a+3]
                + tanhf(e2.x + eh_s[a+4]) * aw_s[a+4] + tanhf(e2.y + eh_s[a+5]) * aw_s[a+5]
                + tanhf(e2.z + eh_s[a+6]) * aw_s[a+6] + tanhf(e2.w + eh_s[a+7]) * aw_s[a+7];
#pragma unroll
        for (int o = 32; o > 0; o >>= 1) s += __shfl_down(s, o, 64);
        if (lane == 0) sc_s[t] = s + ab0;
    }
    __syncthreads();
    if (tid < 64) {
        float v = (tid < T_) ? sc_s[tid] : -INFINITY;
        float m = v;
#pragma unroll
        for (int o = 32; o > 0; o >>= 1) m = fmaxf(m, __shfl_down(m, o, 64));
        m = __shfl(m, 0, 64);
        float e = (tid < T_) ? expf(v - m) : 0.f;
        float su = e;
#pragma unroll
        for (int o = 32; o > 0; o >>= 1) su += __shfl_down(su, o, 64);
        su = __shfl(su, 0, 64);
        if (tid < T_) sc_s[tid] = e / su;
    }
    __syncthreads();
    for (int cc = 0; cc < 8; ++cc) {
        int f = cc * 256 + tid;
        const float* fp = feats + ((long)b * F_ + f) * T_;
        float acc = 0.f;
#pragma unroll
        for (int t4 = 0; t4 < 10; ++t4) {
            float4 v = *(const float4*)(fp + t4 * 4);
            acc += sc_s[t4*4+0] * v.x + sc_s[t4*4+1] * v.y
                 + sc_s[t4*4+2] * v.z + sc_s[t4*4+3] * v.w;
        }
        vh[(long)b * F_ + f] = acc;
    }
}

__global__ void mean_kernel(const float* __restrict__ feats, float* __restrict__ mf)
{
    int idx = blockIdx.x * 256 + threadIdx.x;
    const float* p = feats + (long)idx * T_;
    float s = 0.f;
#pragma unroll
    for (int t = 0; t < T_; t += 4) {
        float4 v = *(const float4*)(p + t);
        s += v.x + v.y + v.z + v.w;
    }
    mf[idx] = s * (1.0f / (float)T_);
}

// dst[c][r] = src[r][c], dst row stride dstld
__global__ void transpose_f32(const float* __restrict__ src, float* __restrict__ dst,
                              int R, int C, int dstld)
{
    __shared__ float t[32][33];
    int c0 = blockIdx.x * 32, r0 = blockIdx.y * 32;
    int x = threadIdx.x & 31, y = threadIdx.x >> 5;
#pragma unroll
    for (int yy = 0; yy < 4; ++yy) {
        int r = r0 + y + yy * 8, c = c0 + x;
        if (r < R && c < C) t[y + yy * 8][x] = src[(long)r * C + c];
    }
    __syncthreads();
#pragma unroll
    for (int yy = 0; yy < 4; ++yy) {
        int c = c0 + y + yy * 8, r = r0 + x;
        if (r < R && c < C) dst[(long)c * dstld + r] = t[x][y + yy * 8];
    }
}

// x1T[1024+e][b] = emb[sents[b][s]][e]
__global__ void wv_gather_kernel(const int* __restrict__ sents, const float* __restrict__ emb,
                                 float* __restrict__ x1T, int s)
{
    __shared__ float t[32][33];
    int e0 = blockIdx.x * 32, b0 = blockIdx.y * 32;
    int x = threadIdx.x & 31, y = threadIdx.x >> 5;
#pragma unroll
    for (int yy = 0; yy < 4; ++yy) {
        int bb = b0 + y + yy * 8;
        int wd = sents[bb * L_ + s];
        t[y + yy * 8][x] = emb[(long)wd * E_ + e0 + x];
    }
    __syncthreads();
#pragma unroll
    for (int yy = 0; yy < 4; ++yy) {
        int e = e0 + y + yy * 8;
        x1T[(long)(1024 + e) * 256 + b0 + x] = t[x][y + yy * 8];
    }
}

__global__ void vec_add_kernel(const float* a, const float* b, float* out, int n)
{
    int i = blockIdx.x * 256 + threadIdx.x;
    if (i < n) out[i] = a[i] + b[i];
}

__global__ __launch_bounds__(256) void argmax_kernel(
    const float* __restrict__ dout_preds, float* __restrict__ outw, int s)
{
    __shared__ float sv[256];
    __shared__ int   si[256];
    int b = blockIdx.x, tid = threadIdx.x;
    const float* row = dout_preds + (long)b * (NS_ * (long)V_) + (long)s * V_;
    float best = -INFINITY; int bi = 0x7fffffff;
    for (int v = tid; v < V_; v += 256) {
        float x = row[v];
        if (x > best) { best = x; bi = v; }
    }
    sv[tid] = best; si[tid] = bi;
    __syncthreads();
    for (int o = 128; o > 0; o >>= 1) {
        if (tid < o) {
            float ov = sv[tid + o]; int oi = si[tid + o];
            if (ov > sv[tid] || (ov == sv[tid] && oi < si[tid])) { sv[tid] = ov; si[tid] = oi; }
        }
        __syncthreads();
    }
    if (tid == 0) outw[b * NS_ + s] = (float)si[0];
}

extern "C" void kernel_launch(void* const* d_in, const int* in_sizes, int n_in,
                              void* d_out, int out_size, void* d_ws, size_t ws_size,
                              hipStream_t stream)
{
    const float* feats  = (const float*)d_in[0];
    const float* atts   = (const float*)d_in[1];
    const int*   sents  = (const int*)d_in[2];
    const float* attr_W = (const float*)d_in[3];
    const float* attr_b = (const float*)d_in[4];
    const float* emb    = (const float*)d_in[5];
    const float* l1_Wih = (const float*)d_in[6];
    const float* l1_Whh = (const float*)d_in[7];
    const float* l1_bih = (const float*)d_in[8];
    const float* l1_bhh = (const float*)d_in[9];
    const float* l2_Wih = (const float*)d_in[10];
    const float* l2_Whh = (const float*)d_in[11];
    const float* l2_bih = (const float*)d_in[12];
    const float* l2_bhh = (const float*)d_in[13];
    const float* prob_W = (const float*)d_in[14];
    const float* prob_b = (const float*)d_in[15];
    const float* attf_W = (const float*)d_in[16];
    const float* attf_b = (const float*)d_in[17];
    const float* atth_W = (const float*)d_in[18];
    const float* atth_b = (const float*)d_in[19];
    const float* atta_W = (const float*)d_in[20];
    const float* atta_b = (const float*)d_in[21];

    float* out = (float*)d_out;
    float* preds = out + B_ * NS_;

    float* w = (float*)d_ws;
    float* x1T     = w;  w += 2560L * 256;   // [h2 | wv | h1]
    float* x2T     = w;  w += 4096L * 256;   // [h1 | vhat | h2]
    float* c1      = w;  w += 1024L * 256;
    float* c2      = w;  w += 1024L * 256;
    float* g1T     = w;  w += 4096L * 256;
    float* g2T     = w;  w += 4096L * 256;
    float* base1T  = w;  w += 4096L * 256;
    float* ef      = w;  w += 10240L * 512;
    float* mf      = w;  w += 256L * 2048;
    float* mfT     = w;  w += 2048L * 256;
    float* attsT   = w;  w += 400L * 256;
    float* attr_vT = w;  w += 3072L * 256;
    float* ehT     = w;  w += 512L * 256;
    float* vh      = w;  w += 256L * 2048;
    float* bihbhh1 = w;  w += 4096;
    float* bias2   = w;  w += 4096;
    float* efbias  = w;  w += 512;
    float* Pbuf    = w;  w += 256L * 10048 * 2;  // >= 5*4096*256 too

    // ---- one-time precompute ----
    hipMemsetAsync(c1, 0, 1024L * 256 * 4, stream);
    hipMemsetAsync(c2, 0, 1024L * 256 * 4, stream);
    hipMemsetAsync(x1T + 1536L * 256, 0, 1024L * 256 * 4, stream);  // h1 = 0

    mean_kernel<<<B_ * F_ / 256, 256, 0, stream>>>(feats, mf);
    transpose_f32<<<dim3(64, 8), 256, 0, stream>>>(mf, mfT, 256, 2048, 256);
    transpose_f32<<<dim3(13, 8), 256, 0, stream>>>(atts, attsT, 256, 400, 256);
    vec_add_kernel<<<16, 256, 0, stream>>>(l1_bih, l1_bhh, bihbhh1, 4096);
    vec_add_kernel<<<16, 256, 0, stream>>>(l2_bih, l2_bhh, bias2, 4096);
    vec_add_kernel<<<2, 256, 0, stream>>>(attf_b, atth_b, efbias, 512);

    // embedf: ef[b*40+t][a], direct write with bias (attf_b + atth_b)
    {
        Chunks8 ch = {};
        ch.c[0] = {attf_W, nullptr, F_, F_};
        gemm_tn<1, 1><<<dim3(8, 80, 1), 256, 0, stream>>>(
            ch, ef, efbias, feats, 512, 512, 0, 0);
    }
    // attr_vT = (atts @ attr_W.T + attr_b)^T
    {
        Chunks8 ch = {};
        for (int z = 0; z < 5; ++z)
            ch.c[z] = {attr_W + z * 80, attsT + (long)z * 80 * 256, ATTR_, 80};
        gemm_tn<0, 0><<<dim3(48, 2, 5), 256, 0, stream>>>(
            ch, Pbuf, nullptr, nullptr, 3072, 0, 3072L * 256, 1);
        reduce_ct<<<768, 256, 0, stream>>>(attr_vT, Pbuf, attr_b, 5, 3072L * 256, 3072 * 256, 2);
    }
    // base1T = (mf @ Wih[:,1024:3072].T)^T + (l1_bih + l1_bhh)
    {
        Chunks8 ch = {};
        for (int z = 0; z < 4; ++z)
            ch.c[z] = {l1_Wih + 1024 + z * 512, mfT + (long)z * 512 * 256, D1_, 512};
        gemm_tn<0, 0><<<dim3(64, 2, 4), 256, 0, stream>>>(
            ch, Pbuf, nullptr, nullptr, 4096, 0, 4096L * 256, 1);
        reduce_ct<<<1024, 256, 0, stream>>>(base1T, Pbuf, bihbhh1, 4, 4096L * 256, 4096 * 256, 2);
    }
    // initial lstm2 on attr_v (h2=0 path): g2 = attr_v @ W2ih.T + biases
    {
        Chunks8 ch = {};
        for (int z = 0; z < 4; ++z)
            ch.c[z] = {l2_Wih + z * 768, attr_vT + (long)z * 768 * 256, D2_, 768};
        gemm_tn<0, 0><<<dim3(64, 2, 4), 256, 0, stream>>>(
            ch, Pbuf, nullptr, nullptr, 4096, 0, 4096L * 256, 1);
        reduce_ct<<<1024, 256, 0, stream>>>(g2T, Pbuf, bias2, 4, 4096L * 256, 4096 * 256, 2);
        lstm_kernel<<<1024, 256, 0, stream>>>(g2T, c2, x1T, x2T + 3072L * 256);
    }

    // static chunk descriptors
    Chunks8 chG1 = {};
    chG1.c[0] = {l1_Wih,        x1T,               D1_, 512};
    chG1.c[1] = {l1_Wih + 512,  x1T + 512L * 256,  D1_, 512};
    chG1.c[2] = {l1_Wih + 3072, x1T + 1024L * 256, D1_, 512};
    chG1.c[3] = {l1_Whh,        x1T + 1536L * 256, H_,  512};
    chG1.c[4] = {l1_Whh + 512,  x1T + 2048L * 256, H_,  512};
    Chunks8 chEh = {};
    for (int z = 0; z < 8; ++z)
        chEh.c[z] = {atth_W + z * 128, x1T + (1536L + z * 128) * 256, H_, 128};
    Chunks8 chG2 = {};
    for (int z = 0; z < 3; ++z)
        chG2.c[z] = {l2_Wih + z * 1024, x2T + (long)z * 1024 * 256, D2_, 1024};
    chG2.c[3] = {l2_Whh, x2T + 3072L * 256, H_, 1024};
    Chunks8 chPr = {};
    for (int z = 0; z < 2; ++z)
        chPr.c[z] = {prob_W + z * 512, x2T + (3072L + z * 512) * 256, H_, 512};

    for (int s = 0; s < NS_; ++s) {
        wv_gather_kernel<<<dim3(16, 8), 256, 0, stream>>>(sents, emb, x1T, s);

        gemm_tn<0, 0><<<dim3(64, 2, 5), 256, 0, stream>>>(
            chG1, Pbuf, nullptr, nullptr, 4096, 0, 4096L * 256, 1);
        reduce_ct<<<1024, 256, 0, stream>>>(g1T, Pbuf, base1T, 5, 4096L * 256, 4096 * 256, 1);
        lstm_kernel<<<1024, 256, 0, stream>>>(g1T, c1, x1T + 1536L * 256, x2T);

        gemm_tn<0, 0><<<dim3(8, 2, 8), 256, 0, stream>>>(
            chEh, Pbuf, nullptr, nullptr, 512, 0, 512L * 256, 1);
        reduce_ct<<<128, 256, 0, stream>>>(ehT, Pbuf, nullptr, 8, 512L * 256, 512 * 256, 0);

        attention_kernel<<<256, 256, 0, stream>>>(ef, ehT, feats, atta_W, atta_b, vh);
        transpose_f32<<<dim3(64, 8), 256, 0, stream>>>(vh, x2T + 1024L * 256, 256, 2048, 256);

        gemm_tn<0, 0><<<dim3(64, 2, 4), 256, 0, stream>>>(
            chG2, Pbuf, nullptr, nullptr, 4096, 0, 4096L * 256, 1);
        reduce_ct<<<1024, 256, 0, stream>>>(g2T, Pbuf, bias2, 4, 4096L * 256, 4096 * 256, 2);
        lstm_kernel<<<1024, 256, 0, stream>>>(g2T, c2, x1T, x2T + 3072L * 256);

        gemm_tn<1, 0><<<dim3(157, 2, 2), 256, 0, stream>>>(
            chPr, Pbuf, nullptr, nullptr, 10000, 10048, 256L * 10048, 1);
        reduce_prob<<<2500, 256, 0, stream>>>(Pbuf, prob_b, out, s);

        argmax_kernel<<<256, 256, 0, stream>>>(preds, out, s);
    }
}